// Round 1
// baseline (135.778 us; speedup 1.0000x reference)
//
#include <hip/hip_runtime.h>
#include <math.h>

#define N_PIX (256 * 256)
#define N_PTS 192

__device__ float g_stats[4];

__global__ __launch_bounds__(256) void render_gray_kernel(
    const float* __restrict__ vol,
    const float* __restrict__ Rm,
    const float* __restrict__ Tv,
    float* __restrict__ gray)
{
    const int pix = blockIdx.x * 256 + threadIdx.x;
    const int h = pix >> 8;
    const int w = pix & 255;
    const float yg = 1.0f - (2.0f / 255.0f) * (float)h;
    const float xg = 1.0f - (2.0f / 255.0f) * (float)w;

    const float r00 = Rm[0], r01 = Rm[1], r02 = Rm[2];
    const float r10 = Rm[3], r11 = Rm[4], r12 = Rm[5];
    const float r20 = Rm[6], r21 = Rm[7], r22 = Rm[8];
    const float t0 = Tv[0], t1 = Tv[1], t2 = Tv[2];

    // world_i(d) = a_i * d + b_i  (linear in depth)
    const float a0 = 0.25f * (r00 * xg + r01 * yg) + r02;
    const float a1 = 0.25f * (r10 * xg + r11 * yg) + r12;
    const float a2 = 0.25f * (r20 * xg + r21 * yg) + r22;
    const float b0 = -(r00 * t0 + r01 * t1 + r02 * t2);
    const float b1 = -(r10 * t0 + r11 * t1 + r12 * t2);
    const float b2 = -(r20 * t0 + r21 * t1 + r22 * t2);

    float absorption = 1.0f;  // cumprod of (1+1e-10 - dens), exclusive
    float opacprod = 1.0f;    // prod of (1 - dens)
    float rgb = 0.0f;

    const float step = 6.0f / 191.0f;
    #pragma unroll 1
    for (int p = 0; p < N_PTS; ++p) {
        const float d = 3.0f + step * (float)p;
        const float fx = (fmaf(a0, d, b0) + 1.0f) * 63.5f;
        const float fy = (fmaf(a1, d, b1) + 1.0f) * 63.5f;
        const float fz = (fmaf(a2, d, b2) + 1.0f) * 63.5f;
        const float x0f = floorf(fx), y0f = floorf(fy), z0f = floorf(fz);
        const float wx = fx - x0f, wy = fy - y0f, wz = fz - z0f;
        const int ix = (int)x0f, iy = (int)y0f, iz = (int)z0f;
        // validity folded into per-axis weights (valid = vx & vy & vz factors)
        const float ax0 = (ix >= 0  && ix <= 127) ? (1.0f - wx) : 0.0f;
        const float ax1 = (ix >= -1 && ix <= 126) ? wx : 0.0f;
        const float ay0 = (iy >= 0  && iy <= 127) ? (1.0f - wy) : 0.0f;
        const float ay1 = (iy >= -1 && iy <= 126) ? wy : 0.0f;
        const float az0 = (iz >= 0  && iz <= 127) ? (1.0f - wz) : 0.0f;
        const float az1 = (iz >= -1 && iz <= 126) ? wz : 0.0f;
        const float s = (ax0 + ax1) * (ay0 + ay1) * (az0 + az1);
        const float dens = s * (1.0f / 192.0f);
        if (s > 0.0f) {
            const int xc0 = min(max(ix, 0), 127);
            const int xc1 = min(max(ix + 1, 0), 127);
            const int yc0 = min(max(iy, 0), 127);
            const int yc1 = min(max(iy + 1, 0), 127);
            const int zc0 = min(max(iz, 0), 127);
            const int zc1 = min(max(iz + 1, 0), 127);
            const float* p00 = vol + (zc0 * 128 + yc0) * 128;
            const float* p01 = vol + (zc0 * 128 + yc1) * 128;
            const float* p10 = vol + (zc1 * 128 + yc0) * 128;
            const float* p11 = vol + (zc1 * 128 + yc1) * 128;
            const float v000 = p00[xc0], v001 = p00[xc1];
            const float v010 = p01[xc0], v011 = p01[xc1];
            const float v100 = p10[xc0], v101 = p10[xc1];
            const float v110 = p11[xc0], v111 = p11[xc1];
            const float feat =
                az0 * (ay0 * (ax0 * v000 + ax1 * v001) + ay1 * (ax0 * v010 + ax1 * v011)) +
                az1 * (ay0 * (ax0 * v100 + ax1 * v101) + ay1 * (ax0 * v110 + ax1 * v111));
            rgb = fmaf(dens * absorption, feat, rgb);
        }
        absorption *= (1.0f + 1e-10f - dens);
        opacprod   *= (1.0f - dens);
    }
    const float g = (3.0f * rgb + (1.0f - opacprod)) * 0.25f;
    gray[pix] = g;
}

__global__ __launch_bounds__(1024) void reduce_stats_kernel(const float* __restrict__ gray)
{
    __shared__ double s_sum[1024];
    __shared__ double s_sq[1024];
    __shared__ float s_mn[1024];
    __shared__ float s_mx[1024];
    double sum = 0.0, sq = 0.0;
    float mn = 1e30f, mx = -1e30f;
    for (int i = threadIdx.x; i < N_PIX; i += 1024) {
        const float g = gray[i];
        sum += (double)g;
        sq += (double)g * (double)g;
        mn = fminf(mn, g);
        mx = fmaxf(mx, g);
    }
    const int tid = threadIdx.x;
    s_sum[tid] = sum; s_sq[tid] = sq; s_mn[tid] = mn; s_mx[tid] = mx;
    __syncthreads();
    for (int off = 512; off > 0; off >>= 1) {
        if (tid < off) {
            s_sum[tid] += s_sum[tid + off];
            s_sq[tid]  += s_sq[tid + off];
            s_mn[tid] = fminf(s_mn[tid], s_mn[tid + off]);
            s_mx[tid] = fmaxf(s_mx[tid], s_mx[tid + off]);
        }
        __syncthreads();
    }
    if (tid == 0) {
        const double N = (double)N_PIX;
        const double mean = s_sum[0] / N;
        double var = (s_sq[0] - N * mean * mean) / (N - 1.0);
        if (var < 0.0) var = 0.0;
        const float denom = (float)sqrt(var) + 1e-8f;
        const float meanf = (float)mean;
        g_stats[0] = meanf;
        g_stats[1] = denom;
        g_stats[2] = (s_mn[0] - meanf) / denom;  // std.min
        g_stats[3] = (s_mx[0] - meanf) / denom;  // std.max
    }
}

__global__ __launch_bounds__(256) void normalize_kernel(float* __restrict__ out)
{
    const int i = blockIdx.x * 256 + threadIdx.x;
    const float mean = g_stats[0];
    const float denom = g_stats[1];
    const float smin = g_stats[2];
    const float smax = g_stats[3];
    const float sv = (out[i] - mean) / denom;
    out[i] = (sv - smin + 1e-8f) / (smax - smin + 1e-8f);
}

extern "C" void kernel_launch(void* const* d_in, const int* in_sizes, int n_in,
                              void* d_out, int out_size, void* d_ws, size_t ws_size,
                              hipStream_t stream)
{
    const float* vol = (const float*)d_in[0];
    const float* Rm  = (const float*)d_in[1];
    const float* Tv  = (const float*)d_in[2];
    float* out = (float*)d_out;

    hipLaunchKernelGGL(render_gray_kernel, dim3(N_PIX / 256), dim3(256), 0, stream,
                       vol, Rm, Tv, out);
    hipLaunchKernelGGL(reduce_stats_kernel, dim3(1), dim3(1024), 0, stream, out);
    hipLaunchKernelGGL(normalize_kernel, dim3(N_PIX / 256), dim3(256), 0, stream, out);
}

// Round 2
// 112.519 us; speedup vs baseline: 1.2067x; 1.2067x over previous
//
#include <hip/hip_runtime.h>
#include <math.h>

#define N_PIX (256 * 256)
#define N_PTS 192
#define SEGS 8
#define SEG_LEN (N_PTS / SEGS)          // 24
#define PIX_PER_BLK 32                  // 256 threads / 8 segs
#define N_BLK (N_PIX / PIX_PER_BLK)     // 2048

__device__ float g_stats[4];

__global__ __launch_bounds__(256) void render_gray_kernel(
    const float* __restrict__ vol,
    const float* __restrict__ Rm,
    const float* __restrict__ Tv,
    float* __restrict__ gray,
    float* __restrict__ part)           // [4][N_BLK] : sum, sq, min, max
{
    const int tid = threadIdx.x;
    const int seg = tid & (SEGS - 1);
    const int pix = blockIdx.x * PIX_PER_BLK + (tid >> 3);
    const int h = pix >> 8;
    const int w = pix & 255;
    const float yg = 1.0f - (2.0f / 255.0f) * (float)h;
    const float xg = 1.0f - (2.0f / 255.0f) * (float)w;

    const float r00 = Rm[0], r01 = Rm[1], r02 = Rm[2];
    const float r10 = Rm[3], r11 = Rm[4], r12 = Rm[5];
    const float r20 = Rm[6], r21 = Rm[7], r22 = Rm[8];
    const float t0 = Tv[0], t1 = Tv[1], t2 = Tv[2];

    // world_i(d) = a_i * d + b_i  (linear in depth)
    const float a0 = 0.25f * (r00 * xg + r01 * yg) + r02;
    const float a1 = 0.25f * (r10 * xg + r11 * yg) + r12;
    const float a2 = 0.25f * (r20 * xg + r21 * yg) + r22;
    const float b0 = -(r00 * t0 + r01 * t1 + r02 * t2);
    const float b1 = -(r10 * t0 + r11 * t1 + r12 * t2);
    const float b2 = -(r20 * t0 + r21 * t1 + r22 * t2);

    float P = 1.0f;   // product of (1+1e-10 - dens) within segment
    float U = 1.0f;   // product of (1 - dens) within segment
    float S = 0.0f;   // sum dens * local_absorption * feat within segment

    const float step = 6.0f / 191.0f;
    const int p0 = seg * SEG_LEN;
    #pragma unroll 2
    for (int i = 0; i < SEG_LEN; ++i) {
        const float d = fmaf(step, (float)(p0 + i), 3.0f);
        const float fx = (fmaf(a0, d, b0) + 1.0f) * 63.5f;
        const float fy = (fmaf(a1, d, b1) + 1.0f) * 63.5f;
        const float fz = (fmaf(a2, d, b2) + 1.0f) * 63.5f;
        const float x0f = floorf(fx), y0f = floorf(fy), z0f = floorf(fz);
        const float wx = fx - x0f, wy = fy - y0f, wz = fz - z0f;
        const int ix = (int)x0f, iy = (int)y0f, iz = (int)z0f;
        // validity folded into per-axis weights
        const float ax0 = (ix >= 0  && ix <= 127) ? (1.0f - wx) : 0.0f;
        const float ax1 = (ix >= -1 && ix <= 126) ? wx : 0.0f;
        const float ay0 = (iy >= 0  && iy <= 127) ? (1.0f - wy) : 0.0f;
        const float ay1 = (iy >= -1 && iy <= 126) ? wy : 0.0f;
        const float az0 = (iz >= 0  && iz <= 127) ? (1.0f - wz) : 0.0f;
        const float az1 = (iz >= -1 && iz <= 126) ? wz : 0.0f;
        const float s = (ax0 + ax1) * (ay0 + ay1) * (az0 + az1);
        const float dens = s * (1.0f / 192.0f);
        if (s > 0.0f) {
            const int xc0 = min(max(ix, 0), 127);
            const int xc1 = min(max(ix + 1, 0), 127);
            const int yc0 = min(max(iy, 0), 127);
            const int yc1 = min(max(iy + 1, 0), 127);
            const int zc0 = min(max(iz, 0), 127);
            const int zc1 = min(max(iz + 1, 0), 127);
            const float* q00 = vol + (zc0 * 128 + yc0) * 128;
            const float* q01 = vol + (zc0 * 128 + yc1) * 128;
            const float* q10 = vol + (zc1 * 128 + yc0) * 128;
            const float* q11 = vol + (zc1 * 128 + yc1) * 128;
            const float v000 = q00[xc0], v001 = q00[xc1];
            const float v010 = q01[xc0], v011 = q01[xc1];
            const float v100 = q10[xc0], v101 = q10[xc1];
            const float v110 = q11[xc0], v111 = q11[xc1];
            const float feat =
                az0 * (ay0 * (ax0 * v000 + ax1 * v001) + ay1 * (ax0 * v010 + ax1 * v011)) +
                az1 * (ay0 * (ax0 * v100 + ax1 * v101) + ay1 * (ax0 * v110 + ax1 * v111));
            S = fmaf(dens * P, feat, S);
        }
        P *= (1.0f + 1e-10f - dens);
        U *= (1.0f - dens);
    }

    // ---- combine 8 depth segments (lanes seg=0..7 of each pixel group) ----
    // inclusive scan of P across the 8-lane group
    float inc = P;
    #pragma unroll
    for (int off = 1; off < SEGS; off <<= 1) {
        const float v = __shfl_up(inc, off, SEGS);
        if (seg >= off) inc *= v;
    }
    float excl = __shfl_up(inc, 1, SEGS);
    if (seg == 0) excl = 1.0f;
    float wS = excl * S;
    #pragma unroll
    for (int off = 1; off < SEGS; off <<= 1) {
        wS += __shfl_xor(wS, off, SEGS);
        U  *= __shfl_xor(U, off, SEGS);
    }

    const bool leader = (seg == 0);
    float g = 0.0f;
    if (leader) {
        g = (3.0f * wS + (1.0f - U)) * 0.25f;
        gray[pix] = g;
    }

    // ---- block stats partials: leaders at lanes {0,8,...,56} of each wave ----
    float vs = leader ? g : 0.0f;
    float vq = leader ? g * g : 0.0f;
    float vmn = leader ? g : 1e30f;
    float vmx = leader ? g : -1e30f;
    #pragma unroll
    for (int off = 8; off < 64; off <<= 1) {
        vs += __shfl_xor(vs, off);
        vq += __shfl_xor(vq, off);
        vmn = fminf(vmn, __shfl_xor(vmn, off));
        vmx = fmaxf(vmx, __shfl_xor(vmx, off));
    }
    __shared__ float s_s[4], s_q[4], s_n[4], s_x[4];
    const int wave = tid >> 6;
    const int lane = tid & 63;
    if (lane == 0) { s_s[wave] = vs; s_q[wave] = vq; s_n[wave] = vmn; s_x[wave] = vmx; }
    __syncthreads();
    if (tid == 0) {
        part[blockIdx.x]             = s_s[0] + s_s[1] + s_s[2] + s_s[3];
        part[N_BLK + blockIdx.x]     = s_q[0] + s_q[1] + s_q[2] + s_q[3];
        part[2 * N_BLK + blockIdx.x] = fminf(fminf(s_n[0], s_n[1]), fminf(s_n[2], s_n[3]));
        part[3 * N_BLK + blockIdx.x] = fmaxf(fmaxf(s_x[0], s_x[1]), fmaxf(s_x[2], s_x[3]));
    }
}

__global__ __launch_bounds__(1024) void stats_kernel(const float* __restrict__ part)
{
    __shared__ float s0[1024], s1[1024], s2[1024], s3[1024];
    const int t = threadIdx.x;
    s0[t] = part[t] + part[t + 1024];
    s1[t] = part[N_BLK + t] + part[N_BLK + t + 1024];
    s2[t] = fminf(part[2 * N_BLK + t], part[2 * N_BLK + t + 1024]);
    s3[t] = fmaxf(part[3 * N_BLK + t], part[3 * N_BLK + t + 1024]);
    __syncthreads();
    for (int off = 512; off > 0; off >>= 1) {
        if (t < off) {
            s0[t] += s0[t + off];
            s1[t] += s1[t + off];
            s2[t] = fminf(s2[t], s2[t + off]);
            s3[t] = fmaxf(s3[t], s3[t + off]);
        }
        __syncthreads();
    }
    if (t == 0) {
        const float N = (float)N_PIX;
        const float mean = s0[0] / N;
        float var = (s1[0] - N * mean * mean) / (N - 1.0f);
        if (var < 0.0f) var = 0.0f;
        const float denom = sqrtf(var) + 1e-8f;
        g_stats[0] = mean;
        g_stats[1] = denom;
        g_stats[2] = (s2[0] - mean) / denom;   // std.min
        g_stats[3] = (s3[0] - mean) / denom;   // std.max
    }
}

__global__ __launch_bounds__(256) void normalize_kernel(float4* __restrict__ out)
{
    const int i = blockIdx.x * 256 + threadIdx.x;
    const float mean = g_stats[0];
    const float rdenom = 1.0f / g_stats[1];
    const float smin = g_stats[2];
    const float rrange = 1.0f / (g_stats[3] - smin + 1e-8f);
    float4 v = out[i];
    v.x = ((v.x - mean) * rdenom - smin + 1e-8f) * rrange;
    v.y = ((v.y - mean) * rdenom - smin + 1e-8f) * rrange;
    v.z = ((v.z - mean) * rdenom - smin + 1e-8f) * rrange;
    v.w = ((v.w - mean) * rdenom - smin + 1e-8f) * rrange;
    out[i] = v;
}

extern "C" void kernel_launch(void* const* d_in, const int* in_sizes, int n_in,
                              void* d_out, int out_size, void* d_ws, size_t ws_size,
                              hipStream_t stream)
{
    const float* vol = (const float*)d_in[0];
    const float* Rm  = (const float*)d_in[1];
    const float* Tv  = (const float*)d_in[2];
    float* out = (float*)d_out;
    float* part = (float*)d_ws;   // 4 * N_BLK floats = 32 KB

    hipLaunchKernelGGL(render_gray_kernel, dim3(N_BLK), dim3(256), 0, stream,
                       vol, Rm, Tv, out, part);
    hipLaunchKernelGGL(stats_kernel, dim3(1), dim3(1024), 0, stream, part);
    hipLaunchKernelGGL(normalize_kernel, dim3(N_PIX / 1024), dim3(256), 0, stream,
                       (float4*)out);
}

// Round 5
// 87.243 us; speedup vs baseline: 1.5563x; 1.2897x over previous
//
#include <hip/hip_runtime.h>
#include <math.h>

#define N_PIX (256 * 256)
#define N_PTS 192
#define SEGS 4
#define PIX_PER_BLK 64                  // 256 threads / 4 segs
#define N_BLK (N_PIX / PIX_PER_BLK)     // 1024

__global__ __launch_bounds__(256) void render_kernel(
    const float* __restrict__ vol,
    const float* __restrict__ Rm,
    const float* __restrict__ Tv,
    float* __restrict__ out,            // gray image (pre-normalization)
    float* __restrict__ part)           // d_ws: [4][N_BLK] sum, sq, min, max
{
    const int tid = threadIdx.x;
    const int seg = tid & (SEGS - 1);
    const int pix = blockIdx.x * PIX_PER_BLK + (tid >> 2);
    const int h = pix >> 8;
    const int w = pix & 255;
    const float yg = 1.0f - (2.0f / 255.0f) * (float)h;
    const float xg = 1.0f - (2.0f / 255.0f) * (float)w;

    const float r00 = Rm[0], r01 = Rm[1], r02 = Rm[2];
    const float r10 = Rm[3], r11 = Rm[4], r12 = Rm[5];
    const float r20 = Rm[6], r21 = Rm[7], r22 = Rm[8];
    const float t0 = Tv[0], t1 = Tv[1], t2 = Tv[2];

    // world_i(d) = a_i * d + b_i  (linear in depth)
    const float a0 = 0.25f * (r00 * xg + r01 * yg) + r02;
    const float a1 = 0.25f * (r10 * xg + r11 * yg) + r12;
    const float a2 = 0.25f * (r20 * xg + r21 * yg) + r22;
    const float b0 = -(r00 * t0 + r01 * t1 + r02 * t2);
    const float b1 = -(r10 * t0 + r11 * t1 + r12 * t2);
    const float b2 = -(r20 * t0 + r21 * t1 + r22 * t2);

    // ---- analytic valid-depth interval: all axes need |a*d+b| < 1 + 2/127 ----
    const float LIM = 1.0f + 2.0f / 127.0f + 1e-4f;
    float dlo = 3.0f, dhi = 9.0f;
    {
        const float aa[3] = {a0, a1, a2};
        const float bb[3] = {b0, b1, b2};
        #pragma unroll
        for (int k = 0; k < 3; ++k) {
            const float a = aa[k], b = bb[k];
            if (fabsf(a) > 1e-12f) {
                const float i0 = (-LIM - b) / a;
                const float i1 = ( LIM - b) / a;
                dlo = fmaxf(dlo, fminf(i0, i1));
                dhi = fminf(dhi, fmaxf(i0, i1));
            } else if (fabsf(b) >= LIM) {
                dhi = -1e30f;   // ray never enters the volume on this axis
            }
        }
    }
    const float step = 6.0f / 191.0f;
    const float rstep = 191.0f / 6.0f;
    int plo = (int)ceilf((dlo - 3.0f) * rstep - 1e-3f);
    int phi = (int)floorf((dhi - 3.0f) * rstep + 1e-3f);
    plo = max(plo, 0);
    phi = min(phi, N_PTS - 1);
    int len = phi - plo + 1;
    if (len < 0) len = 0;
    const int chunk = (len + SEGS - 1) >> 2;
    const int iBeg = plo + seg * chunk;
    const int iEnd = min(iBeg + chunk, plo + len);

    float P = 1.0f;   // product of (1+1e-10 - dens) within my chunk
    float U = 1.0f;   // product of (1 - dens) within my chunk
    float S = 0.0f;   // sum dens * local_absorption * feat within my chunk

    #pragma unroll 2
    for (int p = iBeg; p < iEnd; ++p) {
        const float d = fmaf(step, (float)p, 3.0f);
        const float fx = (fmaf(a0, d, b0) + 1.0f) * 63.5f;
        const float fy = (fmaf(a1, d, b1) + 1.0f) * 63.5f;
        const float fz = (fmaf(a2, d, b2) + 1.0f) * 63.5f;
        const float x0f = floorf(fx), y0f = floorf(fy), z0f = floorf(fz);
        const float wx = fx - x0f, wy = fy - y0f, wz = fz - z0f;
        const int ix = (int)x0f, iy = (int)y0f, iz = (int)z0f;
        // validity folded into per-axis weights
        const float ax0 = (ix >= 0  && ix <= 127) ? (1.0f - wx) : 0.0f;
        const float ax1 = (ix >= -1 && ix <= 126) ? wx : 0.0f;
        const float ay0 = (iy >= 0  && iy <= 127) ? (1.0f - wy) : 0.0f;
        const float ay1 = (iy >= -1 && iy <= 126) ? wy : 0.0f;
        const float az0 = (iz >= 0  && iz <= 127) ? (1.0f - wz) : 0.0f;
        const float az1 = (iz >= -1 && iz <= 126) ? wz : 0.0f;
        const float s = (ax0 + ax1) * (ay0 + ay1) * (az0 + az1);
        const float dens = s * (1.0f / 192.0f);
        // unconditional clamped gathers -> loads pipeline across iterations
        const int xc0 = min(max(ix, 0), 127);
        const int xc1 = min(max(ix + 1, 0), 127);
        const int yc0 = min(max(iy, 0), 127);
        const int yc1 = min(max(iy + 1, 0), 127);
        const int zc0 = min(max(iz, 0), 127);
        const int zc1 = min(max(iz + 1, 0), 127);
        const float* q00 = vol + (zc0 * 128 + yc0) * 128;
        const float* q01 = vol + (zc0 * 128 + yc1) * 128;
        const float* q10 = vol + (zc1 * 128 + yc0) * 128;
        const float* q11 = vol + (zc1 * 128 + yc1) * 128;
        const float v000 = q00[xc0], v001 = q00[xc1];
        const float v010 = q01[xc0], v011 = q01[xc1];
        const float v100 = q10[xc0], v101 = q10[xc1];
        const float v110 = q11[xc0], v111 = q11[xc1];
        const float feat =
            az0 * (ay0 * (ax0 * v000 + ax1 * v001) + ay1 * (ax0 * v010 + ax1 * v011)) +
            az1 * (ay0 * (ax0 * v100 + ax1 * v101) + ay1 * (ax0 * v110 + ax1 * v111));
        S = fmaf(dens * P, feat, S);
        P *= (1.0f + 1e-10f - dens);
        U *= (1.0f - dens);
    }

    // ---- combine 4 depth chunks (lanes seg=0..3 of each pixel group) ----
    float inc = P;
    #pragma unroll
    for (int off = 1; off < SEGS; off <<= 1) {
        const float v = __shfl_up(inc, off, SEGS);
        if (seg >= off) inc *= v;
    }
    float excl = __shfl_up(inc, 1, SEGS);
    if (seg == 0) excl = 1.0f;
    float wS = excl * S;
    #pragma unroll
    for (int off = 1; off < SEGS; off <<= 1) {
        wS += __shfl_xor(wS, off, SEGS);
        U  *= __shfl_xor(U, off, SEGS);
    }

    const bool leader = (seg == 0);
    float g = 0.0f;
    if (leader) {
        g = (3.0f * wS + (1.0f - U)) * 0.25f;
        out[pix] = g;
    }

    // ---- block stats partials (leaders at lanes 0,4,...,60 of each wave) ----
    float vs = leader ? g : 0.0f;
    float vq = leader ? g * g : 0.0f;
    float vmn = leader ? g : 1e30f;
    float vmx = leader ? g : -1e30f;
    #pragma unroll
    for (int off = 4; off < 64; off <<= 1) {
        vs += __shfl_xor(vs, off);
        vq += __shfl_xor(vq, off);
        vmn = fminf(vmn, __shfl_xor(vmn, off));
        vmx = fmaxf(vmx, __shfl_xor(vmx, off));
    }
    __shared__ float s_s[4], s_q[4], s_n[4], s_x[4];
    const int wave = tid >> 6;
    const int lane = tid & 63;
    if (lane == 0) { s_s[wave] = vs; s_q[wave] = vq; s_n[wave] = vmn; s_x[wave] = vmx; }
    __syncthreads();
    if (tid == 0) {
        part[blockIdx.x]             = s_s[0] + s_s[1] + s_s[2] + s_s[3];
        part[N_BLK + blockIdx.x]     = s_q[0] + s_q[1] + s_q[2] + s_q[3];
        part[2 * N_BLK + blockIdx.x] = fminf(fminf(s_n[0], s_n[1]), fminf(s_n[2], s_n[3]));
        part[3 * N_BLK + blockIdx.x] = fmaxf(fmaxf(s_x[0], s_x[1]), fmaxf(s_x[2], s_x[3]));
    }
}

// Every block redundantly reduces the 1024 partials (16 KB, L2/L3-hot),
// then normalizes its own 256 pixels. No cross-block ordering needed.
__global__ __launch_bounds__(256) void finish_kernel(
    float* __restrict__ out,
    const float* __restrict__ part)
{
    const int tid = threadIdx.x;
    __shared__ float s_s[4], s_q[4], s_n[4], s_x[4];
    __shared__ float s_fin[4];

    float fs  = part[tid]               + part[tid + 256]
              + part[tid + 512]         + part[tid + 768];
    float fq  = part[N_BLK + tid]       + part[N_BLK + tid + 256]
              + part[N_BLK + tid + 512] + part[N_BLK + tid + 768];
    float fn  = fminf(fminf(part[2 * N_BLK + tid],       part[2 * N_BLK + tid + 256]),
                      fminf(part[2 * N_BLK + tid + 512], part[2 * N_BLK + tid + 768]));
    float fx2 = fmaxf(fmaxf(part[3 * N_BLK + tid],       part[3 * N_BLK + tid + 256]),
                      fmaxf(part[3 * N_BLK + tid + 512], part[3 * N_BLK + tid + 768]));
    #pragma unroll
    for (int off = 1; off < 64; off <<= 1) {
        fs += __shfl_xor(fs, off);
        fq += __shfl_xor(fq, off);
        fn  = fminf(fn,  __shfl_xor(fn, off));
        fx2 = fmaxf(fx2, __shfl_xor(fx2, off));
    }
    const int wave = tid >> 6;
    const int lane = tid & 63;
    if (lane == 0) { s_s[wave] = fs; s_q[wave] = fq; s_n[wave] = fn; s_x[wave] = fx2; }
    __syncthreads();
    if (tid == 0) {
        const float tsum = s_s[0] + s_s[1] + s_s[2] + s_s[3];
        const float tsq  = s_q[0] + s_q[1] + s_q[2] + s_q[3];
        const float tmn  = fminf(fminf(s_n[0], s_n[1]), fminf(s_n[2], s_n[3]));
        const float tmx  = fmaxf(fmaxf(s_x[0], s_x[1]), fmaxf(s_x[2], s_x[3]));
        const float N = (float)N_PIX;
        const float mean = tsum / N;
        float var = (tsq - N * mean * mean) / (N - 1.0f);
        if (var < 0.0f) var = 0.0f;
        const float denom = sqrtf(var) + 1e-8f;
        s_fin[0] = mean;
        s_fin[1] = denom;
        s_fin[2] = (tmn - mean) / denom;   // std.min
        s_fin[3] = (tmx - mean) / denom;   // std.max
    }
    __syncthreads();

    const float mean = s_fin[0];
    const float rdenom = 1.0f / s_fin[1];
    const float smin = s_fin[2];
    const float rrange = 1.0f / (s_fin[3] - smin + 1e-8f);
    const int i = blockIdx.x * 256 + tid;
    const float sv = (out[i] - mean) * rdenom;
    out[i] = (sv - smin + 1e-8f) * rrange;
}

extern "C" void kernel_launch(void* const* d_in, const int* in_sizes, int n_in,
                              void* d_out, int out_size, void* d_ws, size_t ws_size,
                              hipStream_t stream)
{
    const float* vol = (const float*)d_in[0];
    const float* Rm  = (const float*)d_in[1];
    const float* Tv  = (const float*)d_in[2];
    float* out = (float*)d_out;
    float* part = (float*)d_ws;   // 4 * N_BLK floats = 16 KB

    hipLaunchKernelGGL(render_kernel, dim3(N_BLK), dim3(256), 0, stream,
                       vol, Rm, Tv, out, part);
    hipLaunchKernelGGL(finish_kernel, dim3(N_PIX / 256), dim3(256), 0, stream,
                       out, part);
}